// Round 4
// baseline (1172.439 us; speedup 1.0000x reference)
//
#include <hip/hip_runtime.h>

#define N_ROUTES 512
#define N_TIMES  4096
#define N_MOVES  16384
#define N_NODES  2048
#define N_CDF    8192
#define ALPHA    0.15f
#define NODE_CAP 32    // Binomial(16384,1/2048): mean 8 -> P(>32) negligible

typedef unsigned short ushort_t;
typedef __attribute__((ext_vector_type(8))) short short8;
typedef __attribute__((ext_vector_type(4))) float floatx4;

// ---------------- workspace layout (bytes) ----------------
// Abig  : bf16 [18432*512]   off 0           18,874,368   (rows 0..16383 = A, 16384..18431 = SA)
// xTbf  : bf16 [4096*512]    off 18,874,368   4,194,304
// ncnt  : int  [2048]        off 23,068,672       8,192
// nlist : int  [2048*32]     off 23,076,864     262,144
// w     : f32  [2048]        off 23,339,008       8,192
// basep : f32  [1]           off 23,347,200         256
// yscr  : f32  [4096]        off 23,400,192      16,384   (instrumentation sink)
// total ~23.4 MB
// MEASURED (r3 instrumentation): gemm dispatch ~110 us; budget = fill ~180 +
// out-copy ~80 + pre ~28 + gemm ~110.  This round: nt-stores (L2-thrash fix)
// + peeled tail (no garbage prefetch) + gemm_fused_x3 for counter visibility.

__device__ inline ushort_t f2bf(float f) {
    union { float f; unsigned u; } v; v.f = f;
    unsigned r = (v.u + 0x7FFFu + ((v.u >> 16) & 1u)) >> 16;
    return (ushort_t)r;
}

// xT[t][k] = bf16(relu(x_raw[k][t])) — LDS tile transpose, both sides coalesced.
// Fused: also writes x_out = relu(x_raw) fp32 (output 0), non-temporal (never re-read).
__global__ __launch_bounds__(256) void transpose_bf(const float* __restrict__ xr,
                                                    float* __restrict__ xo,
                                                    ushort_t* __restrict__ xT) {
    __shared__ float ld[64][65];
    int t0 = blockIdx.x * 64;
    int k0 = blockIdx.y * 64;
    int tid = threadIdx.x;
    int col = tid & 63;
    #pragma unroll
    for (int i = 0; i < 16; ++i) {
        int row = i * 4 + (tid >> 6);
        float v = fmaxf(xr[(size_t)(k0 + row) * N_TIMES + t0 + col], 0.f);
        ld[row][col] = v;
        __builtin_nontemporal_store(v, &xo[(size_t)(k0 + row) * N_TIMES + t0 + col]);
    }
    __syncthreads();
    int trow = tid >> 2;
    int kgrp = (tid & 3) * 16;
    ushort_t __align__(16) tmp[16];
    #pragma unroll
    for (int j = 0; j < 16; ++j) tmp[j] = f2bf(ld[kgrp + j][trow]);
    ushort_t* dst = xT + (size_t)(t0 + trow) * 512 + k0 + kgrp;
    *(uint4*)dst       = ((uint4*)tmp)[0];
    *(uint4*)(dst + 8) = ((uint4*)tmp)[1];
}

// A fp32 -> bf16 (0/1 values: exact)
__global__ __launch_bounds__(256) void convA(const float* __restrict__ A,
                                             ushort_t* __restrict__ Ab) {
    size_t i = (size_t)(blockIdx.x * 256 + threadIdx.x) * 8;
    const float4* s = (const float4*)(A + i);
    float4 a = s[0], b = s[1];
    ushort_t __align__(16) t[8] = {f2bf(a.x), f2bf(a.y), f2bf(a.z), f2bf(a.w),
                                   f2bf(b.x), f2bf(b.y), f2bf(b.z), f2bf(b.w)};
    *(uint4*)(Ab + i) = *(uint4*)t;
}

__global__ __launch_bounds__(256) void build_nodes(const int* __restrict__ mnode,
                                                   int* __restrict__ ncnt,
                                                   int* __restrict__ nlist) {
    int m = blockIdx.x * blockDim.x + threadIdx.x;
    if (m >= N_MOVES) return;
    int n = mnode[m];
    int slot = atomicAdd(&ncnt[n], 1);
    if (slot < NODE_CAP) nlist[(size_t)n * NODE_CAP + slot] = m;
}

// SA[n][k] = sum over movements of node n of A[m][k] (small ints, exact in bf16)
__global__ __launch_bounds__(128) void sa_kernel(const float* __restrict__ A,
                                                 const int* __restrict__ ncnt,
                                                 const int* __restrict__ nlist,
                                                 ushort_t* __restrict__ SAb) {
    int n = blockIdx.x, tid = threadIdx.x;
    int cnt = min(ncnt[n], NODE_CAP);
    float acc0 = 0.f, acc1 = 0.f, acc2 = 0.f, acc3 = 0.f;
    for (int j = 0; j < cnt; ++j) {
        int m = nlist[(size_t)n * NODE_CAP + j];
        float4 v = *(const float4*)(A + (size_t)m * 512 + tid * 4);
        acc0 += v.x; acc1 += v.y; acc2 += v.z; acc3 += v.w;
    }
    ushort_t __align__(8) t[4] = {f2bf(acc0), f2bf(acc1), f2bf(acc2), f2bf(acc3)};
    *(uint2*)(SAb + (size_t)n * 512 + tid * 4) = *(uint2*)t;
}

// w[n] = sum_c alpha*t_free*radio/cap^4 ; base = sum_c t_free*radio
__global__ __launch_bounds__(256) void wsum_kernel(const float* __restrict__ t_free,
                                                   const float* __restrict__ cap,
                                                   const float* __restrict__ radio,
                                                   const int* __restrict__ cdf_node,
                                                   float* __restrict__ w,
                                                   float* __restrict__ basep) {
    int c = blockIdx.x * 256 + threadIdx.x;
    float tr = t_free[c] * radio[c];
    float ic = 1.0f / cap[c];
    float ic2 = ic * ic;
    atomicAdd(&w[cdf_node[c]], ALPHA * tr * ic2 * ic2);
    float b = tr;
    #pragma unroll
    for (int d = 32; d >= 1; d >>= 1) b += __shfl_down(b, d);
    if ((threadIdx.x & 63) == 0) atomicAdd(basep, b);
}

__global__ __launch_bounds__(256) void y_init(const float* __restrict__ basep,
                                              float* __restrict__ y) {
    y[blockIdx.x * 256 + threadIdx.x] = *basep;
}

#define GLOAD_LDS16(g, l) __builtin_amdgcn_global_load_lds( \
    (const __attribute__((address_space(1))) void*)(g),     \
    (__attribute__((address_space(3))) void*)(l), 16, 0, 0)

// ============================================================================
// Fused GEMM v4: 256x256 tile, BK=64, 512 thr (8 waves: 2M x 4N, 128x64 each),
// 8-phase schedule, counted vmcnt, setprio, XOR-swizzled LDS, XCD block swizzle.
// v4 changes vs v3:
//   - c_pred epilogue stores are NON-TEMPORAL: the 268 MB write-once stream no
//     longer thrashes L2, so B panels (4.19 MB/XCD working set) stay resident
//     instead of being re-streamed ~9x (H: this was the structure-invariant
//     ~110 us bind: 872 MB fabric traffic at ~8 TB/s).
//   - last K-iteration peeled: no garbage prefetches past K (was +19% reads),
//     no OOB reads; AO(step 7) staged in the peeled iter with vmcnt(0)+barrier.
// Body is a device function so an instrumentation wrapper can run it 3x.
// ============================================================================
__device__ __forceinline__ void gemm_body(const ushort_t* __restrict__ Abig,
                                          const ushort_t* __restrict__ Bbf,
                                          float* __restrict__ c_pred,
                                          const float* __restrict__ w,
                                          float* __restrict__ y) {
    __shared__ __align__(16) ushort_t lds[4][256 * 64];   // AE, AO, BE, BO

    const int tid  = threadIdx.x;
    const int wv   = tid >> 6;          // 0..7
    const int lane = tid & 63;
    const int quad = lane >> 4;
    const int l16  = lane & 15;
    const int wr   = wv >> 2;           // 0..1  M-split
    const int wc   = wv & 3;            // 0..3  N-split

    // XCD-aware bijective swizzle: 1152 blocks = 8 XCDs x 144 (9 bm x 16 bn).
    const int bid = blockIdx.x;
    const int swz = (bid & 7) * 144 + (bid >> 3);
    const int bm  = swz >> 4;           // 0..71
    const int bn  = swz & 15;           // 0..15

    ushort_t* AE = &lds[0][0];
    ushort_t* AO = &lds[1][0];
    ushort_t* BE = &lds[2][0];
    ushort_t* BO = &lds[3][0];

    const ushort_t* gA = Abig + (size_t)bm * 256 * 512;
    const ushort_t* gB = Bbf  + (size_t)bn * 256 * 512;

    const int rr = wv * 8 + (lane >> 3);          // staging row within 64-row group
    const int cl = (lane & 7) ^ (lane >> 3);      // pre-swizzled global chunk

#define STAGE_HALF(T, G, r0, kt) do {                                          \
        GLOAD_LDS16((G) + (size_t)((r0) + rr) * 512 + (kt) * 64 + cl * 8,      \
                    (T) + ((r0) + wv * 8) * 64);                               \
        GLOAD_LDS16((G) + (size_t)((r0) + 64 + rr) * 512 + (kt) * 64 + cl * 8, \
                    (T) + ((r0) + 64 + wv * 8) * 64);                          \
    } while (0)

#define BAR()  asm volatile("s_barrier" ::: "memory")
#define VMC4() asm volatile("s_waitcnt vmcnt(4)" ::: "memory")
#define VMC0() asm volatile("s_waitcnt vmcnt(0)" ::: "memory")

    short8 af[4][2];
    short8 b0[2][2];
    short8 b1[2][2];
    floatx4 acc[8][4] = {};

#define READ_A(T, qm) do {                                                     \
        _Pragma("unroll")                                                      \
        for (int fi = 0; fi < 4; ++fi) {                                       \
            int row = wr * 128 + (qm) * 64 + fi * 16 + l16;                    \
            const ushort_t* p = (T) + row * 64;                                \
            af[fi][0] = *(const short8*)(p + ((quad       ^ (l16 & 7)) * 8));  \
            af[fi][1] = *(const short8*)(p + (((4 + quad) ^ (l16 & 7)) * 8));  \
        }                                                                      \
    } while (0)

#define READ_B(T, qn, B) do {                                                  \
        _Pragma("unroll")                                                      \
        for (int fj = 0; fj < 2; ++fj) {                                       \
            int row = wc * 64 + (qn) * 32 + fj * 16 + l16;                     \
            const ushort_t* p = (T) + row * 64;                                \
            B[fj][0] = *(const short8*)(p + ((quad       ^ (l16 & 7)) * 8));   \
            B[fj][1] = *(const short8*)(p + (((4 + quad) ^ (l16 & 7)) * 8));   \
        }                                                                      \
    } while (0)

#define MFMA_Q(qm, qn, B) do {                                                 \
        __builtin_amdgcn_s_setprio(1);                                         \
        _Pragma("unroll")                                                      \
        for (int kk = 0; kk < 2; ++kk)                                         \
            _Pragma("unroll")                                                  \
            for (int fi = 0; fi < 4; ++fi)                                     \
                _Pragma("unroll")                                              \
                for (int fj = 0; fj < 2; ++fj)                                 \
                    acc[(qm) * 4 + fi][(qn) * 2 + fj] =                        \
                        __builtin_amdgcn_mfma_f32_16x16x32_bf16(               \
                            af[fi][kk], B[fj][kk],                             \
                            acc[(qm) * 4 + fi][(qn) * 2 + fj], 0, 0, 0);       \
        __builtin_amdgcn_s_setprio(0);                                         \
    } while (0)

    // ---- prologue: stage step0 (E.A, E.B) + step1's B (O.B) ----
    STAGE_HALF(AE, gA, 0, 0);   STAGE_HALF(AE, gA, 128, 0);
    STAGE_HALF(BE, gB, 0, 0);   STAGE_HALF(BE, gB, 128, 0);
    STAGE_HALF(BO, gB, 0, 1);   STAGE_HALF(BO, gB, 128, 1);
    VMC4();
    BAR();

    // t=0..2: steady state. Entering iter t: AE,BE hold step 2t; BO holds 2t+1;
    // AO is free (staged this iter with step 2t+1).
    for (int t = 0; t < 3; ++t) {
        const int o  = 2 * t + 1;
        const int e2 = 2 * t + 2;
        const int o2 = 2 * t + 3;

        READ_A(AE, 0); READ_B(BE, 0, b0);
        STAGE_HALF(AO, gA, 0, o);
        BAR(); MFMA_Q(0, 0, b0); BAR();

        READ_B(BE, 1, b1);
        STAGE_HALF(AO, gA, 128, o);
        BAR(); MFMA_Q(0, 1, b1); BAR();

        READ_A(AE, 1);
        STAGE_HALF(BE, gB, 0, e2);
        BAR(); MFMA_Q(1, 0, b0); BAR();

        STAGE_HALF(BE, gB, 128, e2);
        VMC4();
        BAR(); MFMA_Q(1, 1, b1); BAR();

        READ_A(AO, 0); READ_B(BO, 0, b0);
        STAGE_HALF(AE, gA, 0, e2);
        BAR(); MFMA_Q(0, 0, b0); BAR();

        READ_B(BO, 1, b1);
        STAGE_HALF(AE, gA, 128, e2);
        BAR(); MFMA_Q(0, 1, b1); BAR();

        READ_A(AO, 1);
        STAGE_HALF(BO, gB, 0, o2);
        BAR(); MFMA_Q(1, 0, b0); BAR();

        STAGE_HALF(BO, gB, 128, o2);
        VMC4();
        BAR(); MFMA_Q(1, 1, b1); BAR();
    }

    // ---- peeled last iteration: E=step6 (landed), O=step7 (BO landed; AO
    // staged here). Same MFMA order as the unpeeled loop -> bitwise identical.
    READ_A(AE, 0); READ_B(BE, 0, b0);
    STAGE_HALF(AO, gA, 0, 7);
    STAGE_HALF(AO, gA, 128, 7);
    MFMA_Q(0, 0, b0);
    READ_B(BE, 1, b1);
    MFMA_Q(0, 1, b1);
    READ_A(AE, 1);
    MFMA_Q(1, 0, b0);
    MFMA_Q(1, 1, b1);
    VMC0();                        // my AO loads landed
    BAR();                         // everyone's AO loads landed
    READ_A(AO, 0); READ_B(BO, 0, b0); READ_B(BO, 1, b1);
    MFMA_Q(0, 0, b0);
    MFMA_Q(0, 1, b1);
    READ_A(AO, 1);
    MFMA_Q(1, 0, b0);
    MFMA_Q(1, 1, b1);

#undef STAGE_HALF
#undef READ_A
#undef READ_B
#undef MFMA_Q
#undef BAR
#undef VMC4
#undef VMC0

    if (bm < 64) {
        // movement rows: write c_pred, NON-TEMPORAL (write-once stream; keep
        // it out of L2 so B panels stay resident)
        #pragma unroll
        for (int fi = 0; fi < 8; ++fi) {
            #pragma unroll
            for (int reg = 0; reg < 4; ++reg) {
                size_t row = (size_t)bm * 256 + wr * 128 + fi * 16 + quad * 4 + reg;
                float* cp = c_pred + row * N_TIMES + bn * 256 + wc * 64 + l16;
                #pragma unroll
                for (int fj = 0; fj < 4; ++fj)
                    __builtin_nontemporal_store(acc[fi][fj][reg], cp + fj * 16);
            }
        }
    } else {
        // node rows: y[col] += sum_rows w[n] * f^4   (node id == row index)
        int nb = (bm - 64) * 256 + wr * 128;
        float psum[4] = {0.f, 0.f, 0.f, 0.f};
        #pragma unroll
        for (int fj = 0; fj < 4; ++fj)
            #pragma unroll
            for (int fi = 0; fi < 8; ++fi)
                #pragma unroll
                for (int reg = 0; reg < 4; ++reg) {
                    int n = nb + fi * 16 + quad * 4 + reg;
                    float f = acc[fi][fj][reg];
                    float f2 = f * f;
                    psum[fj] += w[n] * f2 * f2;
                }
        #pragma unroll
        for (int fj = 0; fj < 4; ++fj) {
            float v = psum[fj];
            v += __shfl_xor(v, 16);
            v += __shfl_xor(v, 32);
            if (quad == 0)
                atomicAdd(&y[bn * 256 + wc * 64 + fj * 16 + l16], v);
        }
    }
}

__global__ __launch_bounds__(512, 2) void gemm_fused(const ushort_t* __restrict__ Abig,
                                                     const ushort_t* __restrict__ Bbf,
                                                     float* __restrict__ c_pred,
                                                     const float* __restrict__ w,
                                                     float* __restrict__ y) {
    gemm_body(Abig, Bbf, c_pred, w, y);
}

// Instrumentation: 3 full passes back-to-back (~3x gemm duration) so the gemm
// finally exceeds the ~180 us poison fills and lands in rocprof's top-5 with
// its counters. c_pred rewritten idempotently; y-atomics go to a scratch sink.
__global__ __launch_bounds__(512, 2) void gemm_fused_x3(const ushort_t* __restrict__ Abig,
                                                        const ushort_t* __restrict__ Bbf,
                                                        float* __restrict__ c_pred,
                                                        const float* __restrict__ w,
                                                        float* __restrict__ yscr) {
    for (int p = 0; p < 3; ++p) {
        __syncthreads();   // LDS WAR between passes
        gemm_body(Abig, Bbf, c_pred, w, yscr);
    }
}

extern "C" void kernel_launch(void* const* d_in, const int* in_sizes, int n_in,
                              void* d_out, int out_size, void* d_ws, size_t ws_size,
                              hipStream_t stream) {
    const float* x_raw         = (const float*)d_in[0];
    const float* A             = (const float*)d_in[1];
    const float* t_free        = (const float*)d_in[2];
    const float* cap           = (const float*)d_in[3];
    const float* radio         = (const float*)d_in[4];
    const int*   movement_node = (const int*)d_in[5];
    const int*   cdf_node      = (const int*)d_in[6];

    float* out    = (float*)d_out;
    float* x_out  = out;                                  // 512*4096
    float* c_pred = out + (size_t)N_ROUTES * N_TIMES;     // 16384*4096
    float* y      = c_pred + (size_t)N_MOVES * N_TIMES;   // 4096

    char* ws = (char*)d_ws;
    ushort_t* Abig  = (ushort_t*)(ws);                    // 18432*512 bf16
    ushort_t* SAb   = Abig + (size_t)N_MOVES * 512;       // rows 16384..18431
    ushort_t* xTbf  = (ushort_t*)(ws + 18874368);         // 4096*512 bf16
    int*      ncnt  = (int*)(ws + 23068672);
    int*      nlist = (int*)(ws + 23076864);
    float*    w     = (float*)(ws + 23339008);
    float*    basep = (float*)(ws + 23347200);
    float*    yscr  = (float*)(ws + 23400192);            // instrumentation sink

    hipMemsetAsync(ncnt, 0, N_NODES * sizeof(int), stream);
    hipMemsetAsync(w, 0, N_NODES * sizeof(float), stream);
    hipMemsetAsync(basep, 0, sizeof(float), stream);

    transpose_bf<<<dim3(N_TIMES / 64, N_ROUTES / 64), dim3(256), 0, stream>>>(
        x_raw, x_out, xTbf);

    convA<<<dim3((int)((size_t)N_MOVES * 512 / 8 / 256)), dim3(256), 0, stream>>>(A, Abig);

    build_nodes<<<dim3(N_MOVES / 256), dim3(256), 0, stream>>>(movement_node, ncnt, nlist);

    sa_kernel<<<dim3(N_NODES), dim3(128), 0, stream>>>(A, ncnt, nlist, SAb);

    wsum_kernel<<<dim3(N_CDF / 256), dim3(256), 0, stream>>>(
        t_free, cap, radio, cdf_node, w, basep);

    y_init<<<dim3(N_TIMES / 256), dim3(256), 0, stream>>>(basep, y);

    // production gemm
    gemm_fused<<<dim3((N_TIMES / 256) * ((N_MOVES + N_NODES) / 256)), dim3(512), 0, stream>>>(
        Abig, xTbf, c_pred, w, y);
    // instrumentation: 3-pass replica -> visible in rocprof top-5
    gemm_fused_x3<<<dim3((N_TIMES / 256) * ((N_MOVES + N_NODES) / 256)), dim3(512), 0, stream>>>(
        Abig, xTbf, c_pred, w, yscr);
}

// Round 6
// 420.757 us; speedup vs baseline: 2.7865x; 2.7865x over previous
//
#include <hip/hip_runtime.h>

#define N_ROUTES 512
#define N_TIMES  4096
#define N_MOVES  16384
#define N_NODES  2048
#define N_CDF    8192
#define ALPHA    0.15f
#define NODE_CAP 32    // Binomial(16384,1/2048): mean 8 -> P(>32) negligible

typedef unsigned short ushort_t;
typedef __attribute__((ext_vector_type(8))) short short8;
typedef __attribute__((ext_vector_type(4))) float floatx4;

// ---------------- workspace layout (bytes) ----------------
// Abig  : bf16 [18432*512]   off 0           18,874,368   (rows 0..16383 = A, 16384..18431 = SA)
// xTbf  : bf16 [4096*512]    off 18,874,368   4,194,304
// ncnt  : int  [2048]        off 23,068,672       8,192
// nlist : int  [2048*32]     off 23,076,864     262,144
// w     : f32  [2048]        off 23,339,008       8,192
// basep : f32  [1]           off 23,347,200         256
// total ~23.4 MB
// MEASURED (r3/r4 instrumentation): gemm ~107-110 us regardless of schedule;
// x3-replica counters: MfmaUtil 12%, FETCH ~320 MB/pass (ideal 23) -> L2
// thrash from per-XCD working set (all 16 bn panels = 4.19 MB > 4 MiB L2).
// r5 fix: XCD owns 4 bn x 36 bm (bn fastest) -> resident B = 1 MB, A panel
// shared by 4 adjacent blocks; co-resident ws ~3 MB < L2.
// (r5 bench was an infra failure — container died; this is a byte-identical
// resubmit of the same kernel.)

__device__ inline ushort_t f2bf(float f) {
    union { float f; unsigned u; } v; v.f = f;
    unsigned r = (v.u + 0x7FFFu + ((v.u >> 16) & 1u)) >> 16;
    return (ushort_t)r;
}

__device__ inline float bf2f(unsigned u) {
    union { unsigned u; float f; } v; v.u = u << 16; return v.f;
}

// xT[t][k] = bf16(relu(x_raw[k][t])) — LDS tile transpose, both sides coalesced.
// Fused: also writes x_out = relu(x_raw) fp32 (output 0), non-temporal (never re-read).
__global__ __launch_bounds__(256) void transpose_bf(const float* __restrict__ xr,
                                                    float* __restrict__ xo,
                                                    ushort_t* __restrict__ xT) {
    __shared__ float ld[64][65];
    int t0 = blockIdx.x * 64;
    int k0 = blockIdx.y * 64;
    int tid = threadIdx.x;
    int col = tid & 63;
    #pragma unroll
    for (int i = 0; i < 16; ++i) {
        int row = i * 4 + (tid >> 6);
        float v = fmaxf(xr[(size_t)(k0 + row) * N_TIMES + t0 + col], 0.f);
        ld[row][col] = v;
        __builtin_nontemporal_store(v, &xo[(size_t)(k0 + row) * N_TIMES + t0 + col]);
    }
    __syncthreads();
    int trow = tid >> 2;
    int kgrp = (tid & 3) * 16;
    ushort_t __align__(16) tmp[16];
    #pragma unroll
    for (int j = 0; j < 16; ++j) tmp[j] = f2bf(ld[kgrp + j][trow]);
    ushort_t* dst = xT + (size_t)(t0 + trow) * 512 + k0 + kgrp;
    *(uint4*)dst       = ((uint4*)tmp)[0];
    *(uint4*)(dst + 8) = ((uint4*)tmp)[1];
}

// A fp32 -> bf16 (0/1 values: exact)
__global__ __launch_bounds__(256) void convA(const float* __restrict__ A,
                                             ushort_t* __restrict__ Ab) {
    size_t i = (size_t)(blockIdx.x * 256 + threadIdx.x) * 8;
    const float4* s = (const float4*)(A + i);
    float4 a = s[0], b = s[1];
    ushort_t __align__(16) t[8] = {f2bf(a.x), f2bf(a.y), f2bf(a.z), f2bf(a.w),
                                   f2bf(b.x), f2bf(b.y), f2bf(b.z), f2bf(b.w)};
    *(uint4*)(Ab + i) = *(uint4*)t;
}

__global__ __launch_bounds__(256) void build_nodes(const int* __restrict__ mnode,
                                                   int* __restrict__ ncnt,
                                                   int* __restrict__ nlist) {
    int m = blockIdx.x * blockDim.x + threadIdx.x;
    if (m >= N_MOVES) return;
    int n = mnode[m];
    int slot = atomicAdd(&ncnt[n], 1);
    if (slot < NODE_CAP) nlist[(size_t)n * NODE_CAP + slot] = m;
}

// SA[n][k] = sum over movements of node n of Abig[m][k] (bf16 0/1: exact; sums
// <= 32 exact in bf16). Reads the bf16 copy -> half the traffic of fp32 A.
__global__ __launch_bounds__(128) void sa_kernel(const ushort_t* __restrict__ Ab,
                                                 const int* __restrict__ ncnt,
                                                 const int* __restrict__ nlist,
                                                 ushort_t* __restrict__ SAb) {
    int n = blockIdx.x, tid = threadIdx.x;
    int cnt = min(ncnt[n], NODE_CAP);
    float a0 = 0.f, a1 = 0.f, a2 = 0.f, a3 = 0.f;
    for (int j = 0; j < cnt; ++j) {
        int m = nlist[(size_t)n * NODE_CAP + j];
        uint2 v = *(const uint2*)(Ab + (size_t)m * 512 + tid * 4);
        a0 += bf2f(v.x & 0xffffu); a1 += bf2f(v.x >> 16);
        a2 += bf2f(v.y & 0xffffu); a3 += bf2f(v.y >> 16);
    }
    ushort_t __align__(8) t[4] = {f2bf(a0), f2bf(a1), f2bf(a2), f2bf(a3)};
    *(uint2*)(SAb + (size_t)n * 512 + tid * 4) = *(uint2*)t;
}

// w[n] = sum_c alpha*t_free*radio/cap^4 ; base = sum_c t_free*radio
__global__ __launch_bounds__(256) void wsum_kernel(const float* __restrict__ t_free,
                                                   const float* __restrict__ cap,
                                                   const float* __restrict__ radio,
                                                   const int* __restrict__ cdf_node,
                                                   float* __restrict__ w,
                                                   float* __restrict__ basep) {
    int c = blockIdx.x * 256 + threadIdx.x;
    float tr = t_free[c] * radio[c];
    float ic = 1.0f / cap[c];
    float ic2 = ic * ic;
    atomicAdd(&w[cdf_node[c]], ALPHA * tr * ic2 * ic2);
    float b = tr;
    #pragma unroll
    for (int d = 32; d >= 1; d >>= 1) b += __shfl_down(b, d);
    if ((threadIdx.x & 63) == 0) atomicAdd(basep, b);
}

__global__ __launch_bounds__(256) void y_init(const float* __restrict__ basep,
                                              float* __restrict__ y) {
    y[blockIdx.x * 256 + threadIdx.x] = *basep;
}

#define GLOAD_LDS16(g, l) __builtin_amdgcn_global_load_lds( \
    (const __attribute__((address_space(1))) void*)(g),     \
    (__attribute__((address_space(3))) void*)(l), 16, 0, 0)

// ============================================================================
// Fused GEMM v5: 256x256 tile, BK=64, 512 thr (8 waves: 2M x 4N, 128x64 each),
// 8-phase schedule, counted vmcnt, setprio, XOR-swizzled LDS, peeled tail,
// NT c_pred stores.
// v5 change: L2-locality-aware XCD partition. XCD x owns bn in
// [4(x&3), 4(x&3)+3] x bm in [36(x>>2), +35], bn fastest:
//   - resident B set/XCD = 4 panels = 1 MB  -> L2-resident for all 36 bm
//   - A panel read by 4 temporally-adjacent blocks -> 1 fabric fetch
//   - co-resident ws ~3 MB < 4 MiB L2 (was 4.19 MB B alone -> thrash,
//     FETCH ~320 MB vs ideal 23 MB per r4 counters)
// ============================================================================
__device__ __forceinline__ void gemm_body(const ushort_t* __restrict__ Abig,
                                          const ushort_t* __restrict__ Bbf,
                                          float* __restrict__ c_pred,
                                          const float* __restrict__ w,
                                          float* __restrict__ y) {
    __shared__ __align__(16) ushort_t lds[4][256 * 64];   // AE, AO, BE, BO

    const int tid  = threadIdx.x;
    const int wv   = tid >> 6;          // 0..7
    const int lane = tid & 63;
    const int quad = lane >> 4;
    const int l16  = lane & 15;
    const int wr   = wv >> 2;           // 0..1  M-split
    const int wc   = wv & 3;            // 0..3  N-split

    // XCD-partitioned bijective swizzle (1152 = 8 XCD x 144; assumes XCD = bid%8)
    const int bid = blockIdx.x;
    const int xcd = bid & 7;
    const int s   = bid >> 3;           // 0..143
    const int bn  = 4 * (xcd & 3) + (s & 3);     // 0..15, fastest
    const int bm  = 36 * (xcd >> 2) + (s >> 2);  // 0..71

    ushort_t* AE = &lds[0][0];
    ushort_t* AO = &lds[1][0];
    ushort_t* BE = &lds[2][0];
    ushort_t* BO = &lds[3][0];

    const ushort_t* gA = Abig + (size_t)bm * 256 * 512;
    const ushort_t* gB = Bbf  + (size_t)bn * 256 * 512;

    const int rr = wv * 8 + (lane >> 3);          // staging row within 64-row group
    const int cl = (lane & 7) ^ (lane >> 3);      // pre-swizzled global chunk

#define STAGE_HALF(T, G, r0, kt) do {                                          \
        GLOAD_LDS16((G) + (size_t)((r0) + rr) * 512 + (kt) * 64 + cl * 8,      \
                    (T) + ((r0) + wv * 8) * 64);                               \
        GLOAD_LDS16((G) + (size_t)((r0) + 64 + rr) * 512 + (kt) * 64 + cl * 8, \
                    (T) + ((r0) + 64 + wv * 8) * 64);                          \
    } while (0)

#define BAR()  asm volatile("s_barrier" ::: "memory")
#define VMC4() asm volatile("s_waitcnt vmcnt(4)" ::: "memory")
#define VMC0() asm volatile("s_waitcnt vmcnt(0)" ::: "memory")

    short8 af[4][2];
    short8 b0[2][2];
    short8 b1[2][2];
    floatx4 acc[8][4] = {};

#define READ_A(T, qm) do {                                                     \
        _Pragma("unroll")                                                      \
        for (int fi = 0; fi < 4; ++fi) {                                       \
            int row = wr * 128 + (qm) * 64 + fi * 16 + l16;                    \
            const ushort_t* p = (T) + row * 64;                                \
            af[fi][0] = *(const short8*)(p + ((quad       ^ (l16 & 7)) * 8));  \
            af[fi][1] = *(const short8*)(p + (((4 + quad) ^ (l16 & 7)) * 8));  \
        }                                                                      \
    } while (0)

#define READ_B(T, qn, B) do {                                                  \
        _Pragma("unroll")                                                      \
        for (int fj = 0; fj < 2; ++fj) {                                       \
            int row = wc * 64 + (qn) * 32 + fj * 16 + l16;                     \
            const ushort_t* p = (T) + row * 64;                                \
            B[fj][0] = *(const short8*)(p + ((quad       ^ (l16 & 7)) * 8));   \
            B[fj][1] = *(const short8*)(p + (((4 + quad) ^ (l16 & 7)) * 8));   \
        }                                                                      \
    } while (0)

#define MFMA_Q(qm, qn, B) do {                                                 \
        __builtin_amdgcn_s_setprio(1);                                         \
        _Pragma("unroll")                                                      \
        for (int kk = 0; kk < 2; ++kk)                                         \
            _Pragma("unroll")                                                  \
            for (int fi = 0; fi < 4; ++fi)                                     \
                _Pragma("unroll")                                              \
                for (int fj = 0; fj < 2; ++fj)                                 \
                    acc[(qm) * 4 + fi][(qn) * 2 + fj] =                        \
                        __builtin_amdgcn_mfma_f32_16x16x32_bf16(               \
                            af[fi][kk], B[fj][kk],                             \
                            acc[(qm) * 4 + fi][(qn) * 2 + fj], 0, 0, 0);       \
        __builtin_amdgcn_s_setprio(0);                                         \
    } while (0)

    // ---- prologue: stage step0 (E.A, E.B) + step1's B (O.B) ----
    STAGE_HALF(AE, gA, 0, 0);   STAGE_HALF(AE, gA, 128, 0);
    STAGE_HALF(BE, gB, 0, 0);   STAGE_HALF(BE, gB, 128, 0);
    STAGE_HALF(BO, gB, 0, 1);   STAGE_HALF(BO, gB, 128, 1);
    VMC4();
    BAR();

    // t=0..2: steady state. Entering iter t: AE,BE hold step 2t; BO holds 2t+1;
    // AO is free (staged this iter with step 2t+1).
    for (int t = 0; t < 3; ++t) {
        const int o  = 2 * t + 1;
        const int e2 = 2 * t + 2;
        const int o2 = 2 * t + 3;

        READ_A(AE, 0); READ_B(BE, 0, b0);
        STAGE_HALF(AO, gA, 0, o);
        BAR(); MFMA_Q(0, 0, b0); BAR();

        READ_B(BE, 1, b1);
        STAGE_HALF(AO, gA, 128, o);
        BAR(); MFMA_Q(0, 1, b1); BAR();

        READ_A(AE, 1);
        STAGE_HALF(BE, gB, 0, e2);
        BAR(); MFMA_Q(1, 0, b0); BAR();

        STAGE_HALF(BE, gB, 128, e2);
        VMC4();
        BAR(); MFMA_Q(1, 1, b1); BAR();

        READ_A(AO, 0); READ_B(BO, 0, b0);
        STAGE_HALF(AE, gA, 0, e2);
        BAR(); MFMA_Q(0, 0, b0); BAR();

        READ_B(BO, 1, b1);
        STAGE_HALF(AE, gA, 128, e2);
        BAR(); MFMA_Q(0, 1, b1); BAR();

        READ_A(AO, 1);
        STAGE_HALF(BO, gB, 0, o2);
        BAR(); MFMA_Q(1, 0, b0); BAR();

        STAGE_HALF(BO, gB, 128, o2);
        VMC4();
        BAR(); MFMA_Q(1, 1, b1); BAR();
    }

    // ---- peeled last iteration: E=step6 (landed), O=step7 (BO landed; AO
    // staged here). Same MFMA order as the unpeeled loop -> bitwise identical.
    READ_A(AE, 0); READ_B(BE, 0, b0);
    STAGE_HALF(AO, gA, 0, 7);
    STAGE_HALF(AO, gA, 128, 7);
    MFMA_Q(0, 0, b0);
    READ_B(BE, 1, b1);
    MFMA_Q(0, 1, b1);
    READ_A(AE, 1);
    MFMA_Q(1, 0, b0);
    MFMA_Q(1, 1, b1);
    VMC0();                        // my AO loads landed
    BAR();                         // everyone's AO loads landed
    READ_A(AO, 0); READ_B(BO, 0, b0); READ_B(BO, 1, b1);
    MFMA_Q(0, 0, b0);
    MFMA_Q(0, 1, b1);
    READ_A(AO, 1);
    MFMA_Q(1, 0, b0);
    MFMA_Q(1, 1, b1);

#undef STAGE_HALF
#undef READ_A
#undef READ_B
#undef MFMA_Q
#undef BAR
#undef VMC4
#undef VMC0

    if (bm < 64) {
        // movement rows: write c_pred, NON-TEMPORAL (write-once stream; keep
        // it out of L2 so the resident B panels survive)
        #pragma unroll
        for (int fi = 0; fi < 8; ++fi) {
            #pragma unroll
            for (int reg = 0; reg < 4; ++reg) {
                size_t row = (size_t)bm * 256 + wr * 128 + fi * 16 + quad * 4 + reg;
                float* cp = c_pred + row * N_TIMES + bn * 256 + wc * 64 + l16;
                #pragma unroll
                for (int fj = 0; fj < 4; ++fj)
                    __builtin_nontemporal_store(acc[fi][fj][reg], cp + fj * 16);
            }
        }
    } else {
        // node rows: y[col] += sum_rows w[n] * f^4   (node id == row index)
        int nb = (bm - 64) * 256 + wr * 128;
        float psum[4] = {0.f, 0.f, 0.f, 0.f};
        #pragma unroll
        for (int fj = 0; fj < 4; ++fj)
            #pragma unroll
            for (int fi = 0; fi < 8; ++fi)
                #pragma unroll
                for (int reg = 0; reg < 4; ++reg) {
                    int n = nb + fi * 16 + quad * 4 + reg;
                    float f = acc[fi][fj][reg];
                    float f2 = f * f;
                    psum[fj] += w[n] * f2 * f2;
                }
        #pragma unroll
        for (int fj = 0; fj < 4; ++fj) {
            float v = psum[fj];
            v += __shfl_xor(v, 16);
            v += __shfl_xor(v, 32);
            if (quad == 0)
                atomicAdd(&y[bn * 256 + wc * 64 + fj * 16 + l16], v);
        }
    }
}

__global__ __launch_bounds__(512, 2) void gemm_fused(const ushort_t* __restrict__ Abig,
                                                     const ushort_t* __restrict__ Bbf,
                                                     float* __restrict__ c_pred,
                                                     const float* __restrict__ w,
                                                     float* __restrict__ y) {
    gemm_body(Abig, Bbf, c_pred, w, y);
}

extern "C" void kernel_launch(void* const* d_in, const int* in_sizes, int n_in,
                              void* d_out, int out_size, void* d_ws, size_t ws_size,
                              hipStream_t stream) {
    const float* x_raw         = (const float*)d_in[0];
    const float* A             = (const float*)d_in[1];
    const float* t_free        = (const float*)d_in[2];
    const float* cap           = (const float*)d_in[3];
    const float* radio         = (const float*)d_in[4];
    const int*   movement_node = (const int*)d_in[5];
    const int*   cdf_node      = (const int*)d_in[6];

    float* out    = (float*)d_out;
    float* x_out  = out;                                  // 512*4096
    float* c_pred = out + (size_t)N_ROUTES * N_TIMES;     // 16384*4096
    float* y      = c_pred + (size_t)N_MOVES * N_TIMES;   // 4096

    char* ws = (char*)d_ws;
    ushort_t* Abig  = (ushort_t*)(ws);                    // 18432*512 bf16
    ushort_t* SAb   = Abig + (size_t)N_MOVES * 512;       // rows 16384..18431
    ushort_t* xTbf  = (ushort_t*)(ws + 18874368);         // 4096*512 bf16
    int*      ncnt  = (int*)(ws + 23068672);
    int*      nlist = (int*)(ws + 23076864);
    float*    w     = (float*)(ws + 23339008);
    float*    basep = (float*)(ws + 23347200);

    hipMemsetAsync(ncnt, 0, N_NODES * sizeof(int), stream);
    hipMemsetAsync(w, 0, N_NODES * sizeof(float), stream);
    hipMemsetAsync(basep, 0, sizeof(float), stream);

    transpose_bf<<<dim3(N_TIMES / 64, N_ROUTES / 64), dim3(256), 0, stream>>>(
        x_raw, x_out, xTbf);

    convA<<<dim3((int)((size_t)N_MOVES * 512 / 8 / 256)), dim3(256), 0, stream>>>(A, Abig);

    build_nodes<<<dim3(N_MOVES / 256), dim3(256), 0, stream>>>(movement_node, ncnt, nlist);

    sa_kernel<<<dim3(N_NODES), dim3(128), 0, stream>>>(Abig, ncnt, nlist, SAb);

    wsum_kernel<<<dim3(N_CDF / 256), dim3(256), 0, stream>>>(
        t_free, cap, radio, cdf_node, w, basep);

    y_init<<<dim3(N_TIMES / 256), dim3(256), 0, stream>>>(basep, y);

    gemm_fused<<<dim3((N_TIMES / 256) * ((N_MOVES + N_NODES) / 256)), dim3(512), 0, stream>>>(
        Abig, xTbf, c_pred, w, y);
}

// Round 7
// 402.052 us; speedup vs baseline: 2.9161x; 1.0465x over previous
//
#include <hip/hip_runtime.h>

#define N_ROUTES 512
#define N_TIMES  4096
#define N_MOVES  16384
#define N_NODES  2048
#define N_CDF    8192
#define ALPHA    0.15f
#define NODE_CAP 32    // Binomial(16384,1/2048): mean 8 -> P(>32) negligible

typedef unsigned short ushort_t;
typedef __attribute__((ext_vector_type(8))) short short8;
typedef __attribute__((ext_vector_type(4))) float floatx4;

// ---------------- workspace layout (bytes) ----------------
// Abig  : bf16 [18432*512]   off 0           18,874,368   (rows 0..16383 = A, 16384..18431 = SA)
// xTbf  : bf16 [4096*512]    off 18,874,368   4,194,304
// ncnt  : int  [2048]        off 23,068,672       8,192
// nlist : int  [2048*32]     off 23,076,864     262,144
// w     : f32  [2048]        off 23,339,008       8,192
// basep : f32  [1]           off 23,347,200         256
// total ~23.4 MB
// MEASURED: gemm ~110 us invariant across 5 structural variants (schedule,
// occupancy, partition). Model: 604 MB re-reads + 268 MB writes ~= 872 MB
// fabric traffic @ ~8 TB/s ~= 109 us. Reads SHOULD be L3-hits (inputs 23 MB
// << 256 MiB L3) but r4 counters show FETCH ~320 MB/pass: the c_pred write
// stream allocates through L2/L3 and evicts the inputs during the gemm.
// Plain `nt` (r4) did not stop it. r7 experiment (single variable vs r6):
// epilogue stores via inline asm `global_store_dword ... sc0 sc1 nt`
// (no-allocate/bypass at all cache levels).

__device__ inline ushort_t f2bf(float f) {
    union { float f; unsigned u; } v; v.f = f;
    unsigned r = (v.u + 0x7FFFu + ((v.u >> 16) & 1u)) >> 16;
    return (ushort_t)r;
}

__device__ inline float bf2f(unsigned u) {
    union { unsigned u; float f; } v; v.u = u << 16; return v.f;
}

// xT[t][k] = bf16(relu(x_raw[k][t])) — LDS tile transpose, both sides coalesced.
// Fused: also writes x_out = relu(x_raw) fp32 (output 0), non-temporal (never re-read).
__global__ __launch_bounds__(256) void transpose_bf(const float* __restrict__ xr,
                                                    float* __restrict__ xo,
                                                    ushort_t* __restrict__ xT) {
    __shared__ float ld[64][65];
    int t0 = blockIdx.x * 64;
    int k0 = blockIdx.y * 64;
    int tid = threadIdx.x;
    int col = tid & 63;
    #pragma unroll
    for (int i = 0; i < 16; ++i) {
        int row = i * 4 + (tid >> 6);
        float v = fmaxf(xr[(size_t)(k0 + row) * N_TIMES + t0 + col], 0.f);
        ld[row][col] = v;
        __builtin_nontemporal_store(v, &xo[(size_t)(k0 + row) * N_TIMES + t0 + col]);
    }
    __syncthreads();
    int trow = tid >> 2;
    int kgrp = (tid & 3) * 16;
    ushort_t __align__(16) tmp[16];
    #pragma unroll
    for (int j = 0; j < 16; ++j) tmp[j] = f2bf(ld[kgrp + j][trow]);
    ushort_t* dst = xT + (size_t)(t0 + trow) * 512 + k0 + kgrp;
    *(uint4*)dst       = ((uint4*)tmp)[0];
    *(uint4*)(dst + 8) = ((uint4*)tmp)[1];
}

// A fp32 -> bf16 (0/1 values: exact)
__global__ __launch_bounds__(256) void convA(const float* __restrict__ A,
                                             ushort_t* __restrict__ Ab) {
    size_t i = (size_t)(blockIdx.x * 256 + threadIdx.x) * 8;
    const float4* s = (const float4*)(A + i);
    float4 a = s[0], b = s[1];
    ushort_t __align__(16) t[8] = {f2bf(a.x), f2bf(a.y), f2bf(a.z), f2bf(a.w),
                                   f2bf(b.x), f2bf(b.y), f2bf(b.z), f2bf(b.w)};
    *(uint4*)(Ab + i) = *(uint4*)t;
}

__global__ __launch_bounds__(256) void build_nodes(const int* __restrict__ mnode,
                                                   int* __restrict__ ncnt,
                                                   int* __restrict__ nlist) {
    int m = blockIdx.x * blockDim.x + threadIdx.x;
    if (m >= N_MOVES) return;
    int n = mnode[m];
    int slot = atomicAdd(&ncnt[n], 1);
    if (slot < NODE_CAP) nlist[(size_t)n * NODE_CAP + slot] = m;
}

// SA[n][k] = sum over movements of node n of Abig[m][k] (bf16 0/1: exact; sums
// <= 32 exact in bf16). Reads the bf16 copy -> half the traffic of fp32 A.
__global__ __launch_bounds__(128) void sa_kernel(const ushort_t* __restrict__ Ab,
                                                 const int* __restrict__ ncnt,
                                                 const int* __restrict__ nlist,
                                                 ushort_t* __restrict__ SAb) {
    int n = blockIdx.x, tid = threadIdx.x;
    int cnt = min(ncnt[n], NODE_CAP);
    float a0 = 0.f, a1 = 0.f, a2 = 0.f, a3 = 0.f;
    for (int j = 0; j < cnt; ++j) {
        int m = nlist[(size_t)n * NODE_CAP + j];
        uint2 v = *(const uint2*)(Ab + (size_t)m * 512 + tid * 4);
        a0 += bf2f(v.x & 0xffffu); a1 += bf2f(v.x >> 16);
        a2 += bf2f(v.y & 0xffffu); a3 += bf2f(v.y >> 16);
    }
    ushort_t __align__(8) t[4] = {f2bf(a0), f2bf(a1), f2bf(a2), f2bf(a3)};
    *(uint2*)(SAb + (size_t)n * 512 + tid * 4) = *(uint2*)t;
}

// w[n] = sum_c alpha*t_free*radio/cap^4 ; base = sum_c t_free*radio
__global__ __launch_bounds__(256) void wsum_kernel(const float* __restrict__ t_free,
                                                   const float* __restrict__ cap,
                                                   const float* __restrict__ radio,
                                                   const int* __restrict__ cdf_node,
                                                   float* __restrict__ w,
                                                   float* __restrict__ basep) {
    int c = blockIdx.x * 256 + threadIdx.x;
    float tr = t_free[c] * radio[c];
    float ic = 1.0f / cap[c];
    float ic2 = ic * ic;
    atomicAdd(&w[cdf_node[c]], ALPHA * tr * ic2 * ic2);
    float b = tr;
    #pragma unroll
    for (int d = 32; d >= 1; d >>= 1) b += __shfl_down(b, d);
    if ((threadIdx.x & 63) == 0) atomicAdd(basep, b);
}

__global__ __launch_bounds__(256) void y_init(const float* __restrict__ basep,
                                              float* __restrict__ y) {
    y[blockIdx.x * 256 + threadIdx.x] = *basep;
}

#define GLOAD_LDS16(g, l) __builtin_amdgcn_global_load_lds( \
    (const __attribute__((address_space(1))) void*)(g),     \
    (__attribute__((address_space(3))) void*)(l), 16, 0, 0)

// Streaming store: no-allocate / bypass at L2 and MALL (sc0 sc1 nt).
#define STORE_STREAM(p, v, imm) \
    asm volatile("global_store_dword %0, %1, off offset:" #imm " sc0 sc1 nt" \
                 :: "v"(p), "v"(v) : "memory")

// ============================================================================
// Fused GEMM v6: identical to v5 (256x256 tile, BK=64, 8 waves, 8-phase,
// counted vmcnt, setprio, XOR-swizzled LDS, peeled tail, XCD partition)
// EXCEPT the c_pred epilogue uses sc0+sc1+nt streaming stores so the 268 MB
// write-once stream does not evict the L3-resident operands.
// ============================================================================
__device__ __forceinline__ void gemm_body(const ushort_t* __restrict__ Abig,
                                          const ushort_t* __restrict__ Bbf,
                                          float* __restrict__ c_pred,
                                          const float* __restrict__ w,
                                          float* __restrict__ y) {
    __shared__ __align__(16) ushort_t lds[4][256 * 64];   // AE, AO, BE, BO

    const int tid  = threadIdx.x;
    const int wv   = tid >> 6;          // 0..7
    const int lane = tid & 63;
    const int quad = lane >> 4;
    const int l16  = lane & 15;
    const int wr   = wv >> 2;           // 0..1  M-split
    const int wc   = wv & 3;            // 0..3  N-split

    // XCD-partitioned bijective swizzle (1152 = 8 XCD x 144; assumes XCD = bid%8)
    const int bid = blockIdx.x;
    const int xcd = bid & 7;
    const int s   = bid >> 3;           // 0..143
    const int bn  = 4 * (xcd & 3) + (s & 3);     // 0..15, fastest
    const int bm  = 36 * (xcd >> 2) + (s >> 2);  // 0..71

    ushort_t* AE = &lds[0][0];
    ushort_t* AO = &lds[1][0];
    ushort_t* BE = &lds[2][0];
    ushort_t* BO = &lds[3][0];

    const ushort_t* gA = Abig + (size_t)bm * 256 * 512;
    const ushort_t* gB = Bbf  + (size_t)bn * 256 * 512;

    const int rr = wv * 8 + (lane >> 3);          // staging row within 64-row group
    const int cl = (lane & 7) ^ (lane >> 3);      // pre-swizzled global chunk

#define STAGE_HALF(T, G, r0, kt) do {                                          \
        GLOAD_LDS16((G) + (size_t)((r0) + rr) * 512 + (kt) * 64 + cl * 8,      \
                    (T) + ((r0) + wv * 8) * 64);                               \
        GLOAD_LDS16((G) + (size_t)((r0) + 64 + rr) * 512 + (kt) * 64 + cl * 8, \
                    (T) + ((r0) + 64 + wv * 8) * 64);                          \
    } while (0)

#define BAR()  asm volatile("s_barrier" ::: "memory")
#define VMC4() asm volatile("s_waitcnt vmcnt(4)" ::: "memory")
#define VMC0() asm volatile("s_waitcnt vmcnt(0)" ::: "memory")

    short8 af[4][2];
    short8 b0[2][2];
    short8 b1[2][2];
    floatx4 acc[8][4] = {};

#define READ_A(T, qm) do {                                                     \
        _Pragma("unroll")                                                      \
        for (int fi = 0; fi < 4; ++fi) {                                       \
            int row = wr * 128 + (qm) * 64 + fi * 16 + l16;                    \
            const ushort_t* p = (T) + row * 64;                                \
            af[fi][0] = *(const short8*)(p + ((quad       ^ (l16 & 7)) * 8));  \
            af[fi][1] = *(const short8*)(p + (((4 + quad) ^ (l16 & 7)) * 8));  \
        }                                                                      \
    } while (0)

#define READ_B(T, qn, B) do {                                                  \
        _Pragma("unroll")                                                      \
        for (int fj = 0; fj < 2; ++fj) {                                       \
            int row = wc * 64 + (qn) * 32 + fj * 16 + l16;                     \
            const ushort_t* p = (T) + row * 64;                                \
            B[fj][0] = *(const short8*)(p + ((quad       ^ (l16 & 7)) * 8));   \
            B[fj][1] = *(const short8*)(p + (((4 + quad) ^ (l16 & 7)) * 8));   \
        }                                                                      \
    } while (0)

#define MFMA_Q(qm, qn, B) do {                                                 \
        __builtin_amdgcn_s_setprio(1);                                         \
        _Pragma("unroll")                                                      \
        for (int kk = 0; kk < 2; ++kk)                                         \
            _Pragma("unroll")                                                  \
            for (int fi = 0; fi < 4; ++fi)                                     \
                _Pragma("unroll")                                              \
                for (int fj = 0; fj < 2; ++fj)                                 \
                    acc[(qm) * 4 + fi][(qn) * 2 + fj] =                        \
                        __builtin_amdgcn_mfma_f32_16x16x32_bf16(               \
                            af[fi][kk], B[fj][kk],                             \
                            acc[(qm) * 4 + fi][(qn) * 2 + fj], 0, 0, 0);       \
        __builtin_amdgcn_s_setprio(0);                                         \
    } while (0)

    // ---- prologue: stage step0 (E.A, E.B) + step1's B (O.B) ----
    STAGE_HALF(AE, gA, 0, 0);   STAGE_HALF(AE, gA, 128, 0);
    STAGE_HALF(BE, gB, 0, 0);   STAGE_HALF(BE, gB, 128, 0);
    STAGE_HALF(BO, gB, 0, 1);   STAGE_HALF(BO, gB, 128, 1);
    VMC4();
    BAR();

    // t=0..2: steady state. Entering iter t: AE,BE hold step 2t; BO holds 2t+1;
    // AO is free (staged this iter with step 2t+1).
    for (int t = 0; t < 3; ++t) {
        const int o  = 2 * t + 1;
        const int e2 = 2 * t + 2;
        const int o2 = 2 * t + 3;

        READ_A(AE, 0); READ_B(BE, 0, b0);
        STAGE_HALF(AO, gA, 0, o);
        BAR(); MFMA_Q(0, 0, b0); BAR();

        READ_B(BE, 1, b1);
        STAGE_HALF(AO, gA, 128, o);
        BAR(); MFMA_Q(0, 1, b1); BAR();

        READ_A(AE, 1);
        STAGE_HALF(BE, gB, 0, e2);
        BAR(); MFMA_Q(1, 0, b0); BAR();

        STAGE_HALF(BE, gB, 128, e2);
        VMC4();
        BAR(); MFMA_Q(1, 1, b1); BAR();

        READ_A(AO, 0); READ_B(BO, 0, b0);
        STAGE_HALF(AE, gA, 0, e2);
        BAR(); MFMA_Q(0, 0, b0); BAR();

        READ_B(BO, 1, b1);
        STAGE_HALF(AE, gA, 128, e2);
        BAR(); MFMA_Q(0, 1, b1); BAR();

        READ_A(AO, 1);
        STAGE_HALF(BO, gB, 0, o2);
        BAR(); MFMA_Q(1, 0, b0); BAR();

        STAGE_HALF(BO, gB, 128, o2);
        VMC4();
        BAR(); MFMA_Q(1, 1, b1); BAR();
    }

    // ---- peeled last iteration: E=step6 (landed), O=step7 (BO landed; AO
    // staged here). Same MFMA order as the unpeeled loop -> bitwise identical.
    READ_A(AE, 0); READ_B(BE, 0, b0);
    STAGE_HALF(AO, gA, 0, 7);
    STAGE_HALF(AO, gA, 128, 7);
    MFMA_Q(0, 0, b0);
    READ_B(BE, 1, b1);
    MFMA_Q(0, 1, b1);
    READ_A(AE, 1);
    MFMA_Q(1, 0, b0);
    MFMA_Q(1, 1, b1);
    VMC0();                        // my AO loads landed
    BAR();                         // everyone's AO loads landed
    READ_A(AO, 0); READ_B(BO, 0, b0); READ_B(BO, 1, b1);
    MFMA_Q(0, 0, b0);
    MFMA_Q(0, 1, b1);
    READ_A(AO, 1);
    MFMA_Q(1, 0, b0);
    MFMA_Q(1, 1, b1);

#undef STAGE_HALF
#undef READ_A
#undef READ_B
#undef MFMA_Q
#undef BAR
#undef VMC4
#undef VMC0

    if (bm < 64) {
        // movement rows: write c_pred with STREAMING stores (sc0 sc1 nt):
        // no-allocate so the write-once stream leaves L2/L3 operand panels
        // resident. One vaddr per (fi,reg) row; fj via offset immediates.
        #pragma unroll
        for (int fi = 0; fi < 8; ++fi) {
            #pragma unroll
            for (int reg = 0; reg < 4; ++reg) {
                size_t row = (size_t)bm * 256 + wr * 128 + fi * 16 + quad * 4 + reg;
                float* cp = c_pred + row * N_TIMES + bn * 256 + wc * 64 + l16;
                STORE_STREAM(cp, acc[fi][0][reg], 0);
                STORE_STREAM(cp, acc[fi][1][reg], 64);
                STORE_STREAM(cp, acc[fi][2][reg], 128);
                STORE_STREAM(cp, acc[fi][3][reg], 192);
            }
        }
    } else {
        // node rows: y[col] += sum_rows w[n] * f^4   (node id == row index)
        int nb = (bm - 64) * 256 + wr * 128;
        float psum[4] = {0.f, 0.f, 0.f, 0.f};
        #pragma unroll
        for (int fj = 0; fj < 4; ++fj)
            #pragma unroll
            for (int fi = 0; fi < 8; ++fi)
                #pragma unroll
                for (int reg = 0; reg < 4; ++reg) {
                    int n = nb + fi * 16 + quad * 4 + reg;
                    float f = acc[fi][fj][reg];
                    float f2 = f * f;
                    psum[fj] += w[n] * f2 * f2;
                }
        #pragma unroll
        for (int fj = 0; fj < 4; ++fj) {
            float v = psum[fj];
            v += __shfl_xor(v, 16);
            v += __shfl_xor(v, 32);
            if (quad == 0)
                atomicAdd(&y[bn * 256 + wc * 64 + fj * 16 + l16], v);
        }
    }
}

__global__ __launch_bounds__(512, 2) void gemm_fused(const ushort_t* __restrict__ Abig,
                                                     const ushort_t* __restrict__ Bbf,
                                                     float* __restrict__ c_pred,
                                                     const float* __restrict__ w,
                                                     float* __restrict__ y) {
    gemm_body(Abig, Bbf, c_pred, w, y);
}

extern "C" void kernel_launch(void* const* d_in, const int* in_sizes, int n_in,
                              void* d_out, int out_size, void* d_ws, size_t ws_size,
                              hipStream_t stream) {
    const float* x_raw         = (const float*)d_in[0];
    const float* A             = (const float*)d_in[1];
    const float* t_free        = (const float*)d_in[2];
    const float* cap           = (const float*)d_in[3];
    const float* radio         = (const float*)d_in[4];
    const int*   movement_node = (const int*)d_in[5];
    const int*   cdf_node      = (const int*)d_in[6];

    float* out    = (float*)d_out;
    float* x_out  = out;                                  // 512*4096
    float* c_pred = out + (size_t)N_ROUTES * N_TIMES;     // 16384*4096
    float* y      = c_pred + (size_t)N_MOVES * N_TIMES;   // 4096

    char* ws = (char*)d_ws;
    ushort_t* Abig  = (ushort_t*)(ws);                    // 18432*512 bf16
    ushort_t* SAb   = Abig + (size_t)N_MOVES * 512;       // rows 16384..18431
    ushort_t* xTbf  = (ushort_t*)(ws + 18874368);         // 4096*512 bf16
    int*      ncnt  = (int*)(ws + 23068672);
    int*      nlist = (int*)(ws + 23076864);
    float*    w     = (float*)(ws + 23339008);
    float*    basep = (float*)(ws + 23347200);

    hipMemsetAsync(ncnt, 0, N_NODES * sizeof(int), stream);
    hipMemsetAsync(w, 0, N_NODES * sizeof(float), stream);
    hipMemsetAsync(basep, 0, sizeof(float), stream);

    transpose_bf<<<dim3(N_TIMES / 64, N_ROUTES / 64), dim3(256), 0, stream>>>(
        x_raw, x_out, xTbf);

    convA<<<dim3((int)((size_t)N_MOVES * 512 / 8 / 256)), dim3(256), 0, stream>>>(A, Abig);

    build_nodes<<<dim3(N_MOVES / 256), dim3(256), 0, stream>>>(movement_node, ncnt, nlist);

    sa_kernel<<<dim3(N_NODES), dim3(128), 0, stream>>>(Abig, ncnt, nlist, SAb);

    wsum_kernel<<<dim3(N_CDF / 256), dim3(256), 0, stream>>>(
        t_free, cap, radio, cdf_node, w, basep);

    y_init<<<dim3(N_TIMES / 256), dim3(256), 0, stream>>>(basep, y);

    gemm_fused<<<dim3((N_TIMES / 256) * ((N_MOVES + N_NODES) / 256)), dim3(512), 0, stream>>>(
        Abig, xTbf, c_pred, w, y);
}